// Round 2
// baseline (116.117 us; speedup 1.0000x reference)
//
#include <hip/hip_runtime.h>

#define SEQ 79
#define NPAD 80
#define DM 1024
#define BATCHN 512
#define NROWS (BATCHN * SEQ)        // 40448
#define NPAIR (BATCHN * SEQ * SEQ)  // 3,195,392
#define PER_B (32 * NPAD)           // 2560 floats per batch per (u|v) region
#define UVOFF (BATCHN * PER_B)      // v region offset: 1,310,720 floats
#define COFF (2 * UVOFF)            // color region offset: 2,621,440 floats
// total ws floats: COFF + BATCHN*NPAD = 2,662,400 (10.65 MB)

// ---------------- K1: per-(b,n) row -> u'[k][n], v'[k][n], color[n] ------
// One wave per row. Lane l handles x channels c = q*256 + l*4 + t via
// coalesced float4 loads; butterfly-reduce 7 dot products across the wave;
// lanes 0..31 produce u'_k, lanes 32..63 produce v'_k; store TRANSPOSED
// ws[b][k][n] so K2's per-pair reads coalesce.
__global__ __launch_bounds__(256) void k1_embed(
    const float* __restrict__ x,
    const float* __restrict__ piece_w, const float* __restrict__ piece_b,
    const float* __restrict__ color_w, const float* __restrict__ color_b,
    const float* __restrict__ mlp1_w,  const float* __restrict__ mlp1_b,
    float* __restrict__ ws)
{
    const int lane = threadIdx.x & 63;
    const int wid  = (blockIdx.x * blockDim.x + threadIdx.x) >> 6;
    const int nw   = (gridDim.x * blockDim.x) >> 6;
    const int k    = lane & 31;

    // per-lane projection weights: c = q*256 + lane*4 + t, 7 outputs each
    float wp[4][4][7];
#pragma unroll
    for (int q = 0; q < 4; ++q)
#pragma unroll
        for (int t = 0; t < 4; ++t) {
            const int c = q * 256 + lane * 4 + t;
#pragma unroll
            for (int e = 0; e < 6; ++e) wp[q][t][e] = piece_w[c * 6 + e];
            wp[q][t][6] = color_w[c];
        }

    // per-lane u'/v' weights (lane<32 -> u'_k, lane>=32 -> v'_k)
    const bool is_u = (lane < 32);
    float wsp0 = mlp1_w[0 * 32 + k];
    float wsp1 = mlp1_w[1 * 32 + k];
    if (!is_u) { wsp0 = -wsp0; wsp1 = -wsp1; }
    const float bias = is_u ? mlp1_b[k] : 0.0f;
    float wc[6];
#pragma unroll
    for (int c = 0; c < 6; ++c)
        wc[c] = mlp1_w[((is_u ? 2 : 8) + c) * 32 + k];

    float pb[6];
#pragma unroll
    for (int e = 0; e < 6; ++e) pb[e] = piece_b[e];
    const float cb = color_b[0];

    for (int row = wid; row < NROWS; row += nw) {
        const float4* xr = (const float4*)(x + (size_t)row * DM);
        float4 xv[4];
#pragma unroll
        for (int q = 0; q < 4; ++q) xv[q] = xr[q * 64 + lane];

        float acc[7] = {0.f, 0.f, 0.f, 0.f, 0.f, 0.f, 0.f};
#pragma unroll
        for (int q = 0; q < 4; ++q) {
            const float xs[4] = {xv[q].x, xv[q].y, xv[q].z, xv[q].w};
#pragma unroll
            for (int t = 0; t < 4; ++t)
#pragma unroll
                for (int e = 0; e < 7; ++e)
                    acc[e] = fmaf(xs[t], wp[q][t][e], acc[e]);
        }

        // full-wave butterfly reduce: all lanes end with the row sums
#pragma unroll
        for (int e = 0; e < 7; ++e) {
#pragma unroll
            for (int m = 32; m >= 1; m >>= 1)
                acc[e] += __shfl_xor(acc[e], m, 64);
        }

        float p[6];
#pragma unroll
        for (int e = 0; e < 6; ++e) p[e] = acc[e] + pb[e];
        const float col = acc[6] + cb;

        const int b = row / SEQ;
        const int n = row - b * SEQ;
        const float fx = (n < 64) ? (float)(n >> 3) : 0.0f;
        const float fy = (n < 64) ? (float)(n & 7) : 0.0f;

        float val = bias;
        val = fmaf(fx, wsp0, val);
        val = fmaf(fy, wsp1, val);
#pragma unroll
        for (int c = 0; c < 6; ++c) val = fmaf(p[c], wc[c], val);

        // transposed store: ws[(u|v)][b][k][n]
        const size_t base = (size_t)(is_u ? 0 : UVOFF) + (size_t)b * PER_B;
        ws[base + (size_t)k * NPAD + n] = val;
        if (lane == 0) ws[COFF + (size_t)b * NPAD + n] = col;
    }
}

// ---------------- K2: per-(b,i,j) pair MLP ------------------------------
__device__ __forceinline__ float gelu_fast(float a) {
    // 0.5*a*(1+tanh(0.79788456*(a+0.044715*a^3))) = a*(1 - 1/(exp2(c1*a + c2*a^3)+1))
    const float c1 = 2.3022585093f;              // 2*0.7978845608*log2(e)
    const float c2 = 0.1029450750f;              // c1*0.044715
    const float t  = a * fmaf(a * a, c2, c1);
    const float e  = __builtin_amdgcn_exp2f(t);
    const float r  = __builtin_amdgcn_rcpf(e + 1.0f);
    return fmaf(-a, r, a);                       // a - a/(e+1)
}

__global__ __launch_bounds__(256) void k2_pair(
    const float* __restrict__ ws,
    const float* __restrict__ mlp1_w,
    const float* __restrict__ mlp2_w, const float* __restrict__ mlp2_b,
    float* __restrict__ out)
{
    const unsigned p = blockIdx.x * 256u + threadIdx.x;
    if (p >= (unsigned)NPAIR) return;
    const unsigned b = p / (SEQ * SEQ);
    const unsigned r = p - b * (SEQ * SEQ);
    const unsigned i = r / SEQ;
    const unsigned j = r - i * SEQ;

    // u[k] broadcast (i ~wave-uniform), v[k] coalesced (j lane-consecutive)
    const float* ub = ws + (size_t)b * PER_B + i;
    const float* vb = ws + UVOFF + (size_t)b * PER_B + j;

    float u[32], v[32];
#pragma unroll
    for (int k = 0; k < 32; ++k) u[k] = ub[k * NPAD];
#pragma unroll
    for (int k = 0; k < 32; ++k) v[k] = vb[k * NPAD];

    const float ci = ws[COFF + (size_t)b * NPAD + i];
    const float cj = ws[COFF + (size_t)b * NPAD + j];
    const float same = (ci == cj) ? 1.0f : 0.0f;

    float acc[8] = {0.f, 0.f, 0.f, 0.f, 0.f, 0.f, 0.f, 0.f};
#pragma unroll
    for (int k = 0; k < 32; ++k) {
        float a = u[k] + v[k];
        a = fmaf(same, mlp1_w[14 * 32 + k], a);   // uniform -> s_load
        const float h = gelu_fast(a);
#pragma unroll
        for (int e = 0; e < 8; ++e)
            acc[e] = fmaf(h, mlp2_w[k * 8 + e], acc[e]);  // uniform -> s_load
    }

    const size_t ob = (size_t)b * (8 * SEQ * SEQ) + (size_t)i * SEQ + j;
#pragma unroll
    for (int e = 0; e < 8; ++e)
        out[ob + (size_t)e * (SEQ * SEQ)] = acc[e] + mlp2_b[e];
}

extern "C" void kernel_launch(void* const* d_in, const int* in_sizes, int n_in,
                              void* d_out, int out_size, void* d_ws, size_t ws_size,
                              hipStream_t stream) {
    const float* x       = (const float*)d_in[0];
    const float* piece_w = (const float*)d_in[1];
    const float* piece_b = (const float*)d_in[2];
    const float* color_w = (const float*)d_in[3];
    const float* color_b = (const float*)d_in[4];
    const float* mlp1_w  = (const float*)d_in[5];
    const float* mlp1_b  = (const float*)d_in[6];
    const float* mlp2_w  = (const float*)d_in[7];
    const float* mlp2_b  = (const float*)d_in[8];
    float* out = (float*)d_out;
    float* ws  = (float*)d_ws;   // needs 2,662,400 floats = 10.65 MB

    hipLaunchKernelGGL(k1_embed, dim3(2048), dim3(256), 0, stream,
                       x, piece_w, piece_b, color_w, color_b, mlp1_w, mlp1_b, ws);
    hipLaunchKernelGGL(k2_pair, dim3((NPAIR + 255) / 256), dim3(256), 0, stream,
                       ws, mlp1_w, mlp2_w, mlp2_b, out);
}